// Round 3
// baseline (2171.838 us; speedup 1.0000x reference)
//
#include <hip/hip_runtime.h>
#include <stdint.h>

#define T_REL 3
#define F_IN  128
#define F_HID 128
#define F_OUT 64

#define BSHIFT 7                 // 128 dst nodes per bucket
#define BRANGE (1 << BSHIFT)
#define BCAP   3072              // mean 2048, sigma ~45 -> 22 sigma headroom

// ===========================================================================
// Bucketed counting-sort CSR build (dense writes; no 4B-random-scatter).
// ===========================================================================

// bin: append packed (local_dst<<17 | src) to bucket d>>7; cursor-sequential
// slots => dense line fills.
__global__ __launch_bounds__(256) void bin_kernel(
    int* __restrict__ bucketCount, uint32_t* __restrict__ binned,
    const int* __restrict__ edges, int E, int KB)
{
    int t = blockIdx.y;
    int e = blockIdx.x * blockDim.x + threadIdx.x;
    if (e >= E) return;
    int s = edges[(size_t)(t * 2) * E + e];
    int d = edges[(size_t)(t * 2 + 1) * E + e];
    int b = d >> BSHIFT;
    int pos = atomicAdd(&bucketCount[t * KB + b], 1);
    if (pos < BCAP)
        binned[((size_t)t * KB + b) * BCAP + pos] =
            ((uint32_t)(d & (BRANGE - 1)) << 17) | (uint32_t)s;
}

// exclusive scan of bucket counts (one block per relation, KB <= 1024)
__global__ __launch_bounds__(1024) void bucket_scan_kernel(
    const int* __restrict__ bucketCount, int* __restrict__ bucketStart,
    int* __restrict__ rp, int KB, int N, int E)
{
    int t = blockIdx.x;
    int tid = threadIdx.x;
    __shared__ int sh[1024];
    int v = (tid < KB) ? bucketCount[t * KB + tid] : 0;
    sh[tid] = v;
    __syncthreads();
    for (int off = 1; off < 1024; off <<= 1) {
        int x = (tid >= off) ? sh[tid - off] : 0;
        __syncthreads();
        sh[tid] += x;
        __syncthreads();
    }
    if (tid < KB) bucketStart[t * (KB + 1) + tid] = sh[tid] - v;
    if (tid == 0) {
        bucketStart[t * (KB + 1) + KB] = E;
        rp[(size_t)t * (N + 1) + N] = E;
    }
}

// per-bucket: LDS histogram (=> rp, dinv) + LDS cursor scatter => dense srcs
__global__ __launch_bounds__(256) void bucket_sort_kernel(
    const int* __restrict__ bucketCount, const int* __restrict__ bucketStart,
    const uint32_t* __restrict__ binned, int* __restrict__ srcs,
    int* __restrict__ rp, float* __restrict__ dinv,
    int KB, int N, int E)
{
    int t = blockIdx.y, b = blockIdx.x, tid = threadIdx.x;
    int base = b << BSHIFT;
    int cnt = bucketCount[t * KB + b];
    if (cnt > BCAP) cnt = BCAP;
    int bstart = bucketStart[t * (KB + 1) + b];

    __shared__ uint32_t eL[BCAP];
    __shared__ int hist[BRANGE];
    __shared__ int excl[BRANGE];
    __shared__ int cur[BRANGE];

    if (tid < BRANGE) hist[tid] = 0;
    __syncthreads();

    const uint32_t* bin = binned + ((size_t)t * KB + b) * BCAP;
    for (int i = tid; i < cnt; i += 256) {
        uint32_t v = bin[i];
        eL[i] = v;
        atomicAdd(&hist[v >> 17], 1);
    }
    __syncthreads();

    // exclusive scan of hist[0..128) using threads 0..127 (2 waves, barriers)
    if (tid < BRANGE) excl[tid] = hist[tid];
    __syncthreads();
    for (int off = 1; off < BRANGE; off <<= 1) {
        int x = (tid < BRANGE && tid >= off) ? excl[tid - off] : 0;
        __syncthreads();
        if (tid < BRANGE) excl[tid] += x;
        __syncthreads();
    }
    // excl now inclusive; convert on use
    if (tid < BRANGE) {
        int e_ = excl[tid] - hist[tid];      // exclusive
        cur[tid] = e_;
        int g = base + tid;
        if (g < N) {
            rp[(size_t)t * (N + 1) + g] = bstart + e_;
            dinv[(size_t)t * N + g] = rsqrtf(1.0f + (float)hist[tid]);
        }
    }
    __syncthreads();

    int* so = srcs + (size_t)t * E + bstart;
    for (int i = tid; i < cnt; i += 256) {
        uint32_t v = eL[i];
        int slot = atomicAdd(&cur[v >> 17], 1);
        so[slot] = (int)(v & 0x1FFFF);
    }
}

// ===========================================================================
// fp32 GEMM: H[N x BN] = act(X[N x 128]) @ W[128 x BN]   (unchanged)
// ===========================================================================
template<int BN, int TN, bool RELU>
__global__ __launch_bounds__(256) void gemm_kernel(
    const float* __restrict__ X, const float* __restrict__ W,
    float* __restrict__ H, int N)
{
    constexpr int BM = 128;
    constexpr int K  = 128;
    constexpr int TM = 8;
    constexpr int XS_STRIDE = K + 4;

    __shared__ float Xs[BM * XS_STRIDE];
    __shared__ float Ws[K * BN];

    const int tid  = threadIdx.x;
    const int row0 = blockIdx.x * BM;

    constexpr int XV = BM * K / 4;
    for (int i = tid; i < XV; i += 256) {
        int r  = i >> 5;
        int c4 = i & 31;
        float4 v = make_float4(0.f, 0.f, 0.f, 0.f);
        int gr = row0 + r;
        if (gr < N) {
            v = reinterpret_cast<const float4*>(X + (size_t)gr * K)[c4];
            if (RELU) {
                v.x = fmaxf(v.x, 0.f); v.y = fmaxf(v.y, 0.f);
                v.z = fmaxf(v.z, 0.f); v.w = fmaxf(v.w, 0.f);
            }
        }
        *reinterpret_cast<float4*>(&Xs[r * XS_STRIDE + c4 * 4]) = v;
    }
    constexpr int WV = K * BN / 4;
    {
        const float4* W4  = reinterpret_cast<const float4*>(W);
        float4*       Ws4 = reinterpret_cast<float4*>(Ws);
        for (int i = tid; i < WV; i += 256) Ws4[i] = W4[i];
    }
    __syncthreads();

    const int tx = tid & 15;
    const int ty = tid >> 4;

    float acc[TM][TN];
#pragma unroll
    for (int m = 0; m < TM; ++m)
#pragma unroll
        for (int n = 0; n < TN; ++n) acc[m][n] = 0.f;

#pragma unroll 4
    for (int k = 0; k < K; ++k) {
        float a[TM];
#pragma unroll
        for (int m = 0; m < TM; ++m)
            a[m] = Xs[(ty + m * 16) * XS_STRIDE + k];
        float b[TN];
        const float* wrow = &Ws[k * BN + tx * TN];
#pragma unroll
        for (int n = 0; n < TN; n += 4) {
            float4 bv = *reinterpret_cast<const float4*>(wrow + n);
            b[n] = bv.x; b[n + 1] = bv.y; b[n + 2] = bv.z; b[n + 3] = bv.w;
        }
#pragma unroll
        for (int m = 0; m < TM; ++m)
#pragma unroll
            for (int n = 0; n < TN; ++n)
                acc[m][n] = fmaf(a[m], b[n], acc[m][n]);
    }

#pragma unroll
    for (int m = 0; m < TM; ++m) {
        int gr = row0 + ty + m * 16;
        if (gr < N) {
            float* orow = H + (size_t)gr * BN + tx * TN;
#pragma unroll
            for (int n = 0; n < TN; n += 4) {
                *reinterpret_cast<float4*>(orow + n) =
                    make_float4(acc[m][n], acc[m][n + 1], acc[m][n + 2], acc[m][n + 3]);
            }
        }
    }
}

// ===========================================================================
// CSR gather: one wave per dst node; lane owns 2 feature cols. (unchanged)
// ===========================================================================
template<int F>
__global__ __launch_bounds__(256) void gather_csr_kernel(
    float* __restrict__ out, const float* __restrict__ H,
    const float* __restrict__ dinv, const int* __restrict__ rp,
    const int* __restrict__ srcs, const float* __restrict__ bias,
    int N, int accum)
{
    int wave = threadIdx.x >> 6;
    int lane = threadIdx.x & 63;
    int i = blockIdx.x * 4 + wave;
    if (i >= N) return;
    int c = lane * 2;
    if (c >= F) return;

    int beg = rp[i], end = rp[i + 1];
    float ax = 0.f, ay = 0.f;
    int j = beg;
    for (; j + 4 <= end; j += 4) {
        int s0 = srcs[j], s1 = srcs[j + 1], s2 = srcs[j + 2], s3 = srcs[j + 3];
        float d0 = dinv[s0], d1 = dinv[s1], d2 = dinv[s2], d3 = dinv[s3];
        float2 h0 = *reinterpret_cast<const float2*>(H + (size_t)s0 * F + c);
        float2 h1 = *reinterpret_cast<const float2*>(H + (size_t)s1 * F + c);
        float2 h2 = *reinterpret_cast<const float2*>(H + (size_t)s2 * F + c);
        float2 h3 = *reinterpret_cast<const float2*>(H + (size_t)s3 * F + c);
        ax = fmaf(h0.x, d0, fmaf(h1.x, d1, fmaf(h2.x, d2, fmaf(h3.x, d3, ax))));
        ay = fmaf(h0.y, d0, fmaf(h1.y, d1, fmaf(h2.y, d2, fmaf(h3.y, d3, ay))));
    }
    for (; j < end; ++j) {
        int s = srcs[j];
        float d = dinv[s];
        float2 h = *reinterpret_cast<const float2*>(H + (size_t)s * F + c);
        ax = fmaf(h.x, d, ax);
        ay = fmaf(h.y, d, ay);
    }
    float di = dinv[i];
    float2 hs = *reinterpret_cast<const float2*>(H + (size_t)i * F + c);
    float2 bv = *reinterpret_cast<const float2*>(bias + c);
    float rx = (ax * di + hs.x * di * di + bv.x) * (1.0f / 3.0f);
    float ry = (ay * di + hs.y * di * di + bv.y) * (1.0f / 3.0f);
    float* op = out + (size_t)i * F + c;
    if (accum) { rx += op[0]; ry += op[1]; }
    *reinterpret_cast<float2*>(op) = make_float2(rx, ry);
}

// ===========================================================================
extern "C" void kernel_launch(void* const* d_in, const int* in_sizes, int n_in,
                              void* d_out, int out_size, void* d_ws, size_t ws_size,
                              hipStream_t stream) {
    const float* x     = (const float*)d_in[0];
    const int*   edges = (const int*)  d_in[1];
    const float* W1    = (const float*)d_in[2];
    const float* b1    = (const float*)d_in[3];
    const float* W2    = (const float*)d_in[4];
    const float* b2    = (const float*)d_in[5];
    float* out = (float*)d_out;

    const int N = in_sizes[0] / F_IN;
    const int E = in_sizes[1] / (T_REL * 2);
    const int KB = (N + BRANGE - 1) >> BSHIFT;      // buckets per relation

    // ---- workspace layout (256B-aligned chunks) ----
    auto align256 = [](size_t x) { return (x + 255) & ~(size_t)255; };
    char* p = (char*)d_ws;
    float* dinv    = (float*)p;  p += align256((size_t)T_REL * N * 4);
    int*   rp      = (int*)p;    p += align256((size_t)T_REL * (N + 1) * 4);
    int*   bcnt    = (int*)p;    p += align256((size_t)T_REL * KB * 4);
    int*   bstart  = (int*)p;    p += align256((size_t)T_REL * (KB + 1) * 4);
    int*   srcs    = (int*)p;    p += align256((size_t)T_REL * E * 4);
    float* Hbuf    = (float*)p;  p += align256((size_t)N * F_HID * 4);
    float* h1      = (float*)p;
    // binned (29 MB) overlays Hbuf (51 MB): dead before first GEMM writes Hbuf
    uint32_t* binned = (uint32_t*)Hbuf;

    const int B = 256;

    // ---- CSR build: bin -> scan -> per-bucket sort (also emits rp, dinv) ----
    hipMemsetAsync(bcnt, 0, (size_t)T_REL * KB * sizeof(int), stream);
    {
        dim3 g((E + B - 1) / B, T_REL);
        bin_kernel<<<g, B, 0, stream>>>(bcnt, binned, edges, E, KB);
    }
    bucket_scan_kernel<<<T_REL, 1024, 0, stream>>>(bcnt, bstart, rp, KB, N, E);
    {
        dim3 g(KB, T_REL);
        bucket_sort_kernel<<<g, B, 0, stream>>>(bcnt, bstart, binned, srcs,
                                                rp, dinv, KB, N, E);
    }

    const int gather_grid = (N + 3) / 4;

    // ---- layer 1: h1 = mean_t( GCNConv(x@W1[t]) + b1[t] ) ----
    for (int t = 0; t < T_REL; ++t) {
        gemm_kernel<128, 8, false><<<(N + 127) / 128, 256, 0, stream>>>(
            x, W1 + (size_t)t * F_IN * F_HID, Hbuf, N);
        gather_csr_kernel<128><<<gather_grid, 256, 0, stream>>>(
            h1, Hbuf, dinv + (size_t)t * N, rp + (size_t)t * (N + 1),
            srcs + (size_t)t * E, b1 + (size_t)t * F_HID, N, t > 0 ? 1 : 0);
    }

    // ---- layer 2: out = mean_t( GCNConv(relu(h1)@W2[t]) + b2[t] ) ----
    for (int t = 0; t < T_REL; ++t) {
        gemm_kernel<64, 4, true><<<(N + 127) / 128, 256, 0, stream>>>(
            h1, W2 + (size_t)t * F_HID * F_OUT, Hbuf, N);
        gather_csr_kernel<64><<<gather_grid, 256, 0, stream>>>(
            out, Hbuf, dinv + (size_t)t * N, rp + (size_t)t * (N + 1),
            srcs + (size_t)t * E, b2 + (size_t)t * F_OUT, N, t > 0 ? 1 : 0);
    }
}

// Round 4
// 1384.935 us; speedup vs baseline: 1.5682x; 1.5682x over previous
//
#include <hip/hip_runtime.h>
#include <stdint.h>

#define T_REL 3
#define F_IN  128
#define F_HID 128
#define F_OUT 64

#define BSHIFT 7                 // 128 dst nodes per bucket
#define BRANGE (1 << BSHIFT)
#define BCAP   3072              // mean 2048, sigma ~45 -> 22 sigma headroom
#define KB_MAX 1024
#define CHUNK_E 16384            // edges per bin block

// ===========================================================================
// Bucketed counting-sort CSR build.
// bin: LDS-aggregated two-pass — per-block LDS histogram, ONE global atomic
// per (block,bucket) to reserve a range, then dense in-range writes.
// ===========================================================================
__global__ __launch_bounds__(256) void bin_kernel(
    int* __restrict__ bucketCount, uint32_t* __restrict__ binned,
    const int* __restrict__ edges, int E, int KB)
{
    int t = blockIdx.y;
    int tid = threadIdx.x;
    int e0 = blockIdx.x * CHUNK_E;
    int eend = min(e0 + CHUNK_E, E);

    __shared__ int hist[KB_MAX];
    __shared__ int base[KB_MAX];

    for (int b = tid; b < KB; b += 256) hist[b] = 0;
    __syncthreads();

    const int* srcA = edges + (size_t)(t * 2) * E;
    const int* dstA = edges + (size_t)(t * 2 + 1) * E;

    // pass 1: LDS histogram of buckets
    for (int i = e0 + tid; i < eend; i += 256)
        atomicAdd(&hist[dstA[i] >> BSHIFT], 1);
    __syncthreads();

    // reserve contiguous ranges: one global atomic per (block,bucket)
    for (int b = tid; b < KB; b += 256) {
        int h = hist[b];
        base[b] = h ? atomicAdd(&bucketCount[t * KB + b], h) : 0;
        hist[b] = 0;                        // reuse as in-range cursor
    }
    __syncthreads();

    // pass 2: write packed (local_dst<<17 | src) into reserved dense ranges
    for (int i = e0 + tid; i < eend; i += 256) {
        int s = srcA[i];
        int d = dstA[i];
        int b = d >> BSHIFT;
        int pos = base[b] + atomicAdd(&hist[b], 1);
        if (pos < BCAP)
            binned[((size_t)t * KB + b) * BCAP + pos] =
                ((uint32_t)(d & (BRANGE - 1)) << 17) | (uint32_t)s;
    }
}

// exclusive scan of bucket counts (one block per relation, KB <= 1024)
__global__ __launch_bounds__(1024) void bucket_scan_kernel(
    const int* __restrict__ bucketCount, int* __restrict__ bucketStart,
    int* __restrict__ rp, int KB, int N, int E)
{
    int t = blockIdx.x;
    int tid = threadIdx.x;
    __shared__ int sh[1024];
    int v = (tid < KB) ? bucketCount[t * KB + tid] : 0;
    sh[tid] = v;
    __syncthreads();
    for (int off = 1; off < 1024; off <<= 1) {
        int x = (tid >= off) ? sh[tid - off] : 0;
        __syncthreads();
        sh[tid] += x;
        __syncthreads();
    }
    if (tid < KB) bucketStart[t * (KB + 1) + tid] = sh[tid] - v;
    if (tid == 0) {
        bucketStart[t * (KB + 1) + KB] = E;
        rp[(size_t)t * (N + 1) + N] = E;
    }
}

// per-bucket: LDS histogram (=> rp, dinv) + LDS cursor scatter => dense srcs
__global__ __launch_bounds__(256) void bucket_sort_kernel(
    const int* __restrict__ bucketCount, const int* __restrict__ bucketStart,
    const uint32_t* __restrict__ binned, int* __restrict__ srcs,
    int* __restrict__ rp, float* __restrict__ dinv,
    int KB, int N, int E)
{
    int t = blockIdx.y, b = blockIdx.x, tid = threadIdx.x;
    int base = b << BSHIFT;
    int cnt = bucketCount[t * KB + b];
    if (cnt > BCAP) cnt = BCAP;
    int bstart = bucketStart[t * (KB + 1) + b];

    __shared__ uint32_t eL[BCAP];
    __shared__ int hist[BRANGE];
    __shared__ int excl[BRANGE];
    __shared__ int cur[BRANGE];

    if (tid < BRANGE) hist[tid] = 0;
    __syncthreads();

    const uint32_t* bin = binned + ((size_t)t * KB + b) * BCAP;
    for (int i = tid; i < cnt; i += 256) {
        uint32_t v = bin[i];
        eL[i] = v;
        atomicAdd(&hist[v >> 17], 1);
    }
    __syncthreads();

    if (tid < BRANGE) excl[tid] = hist[tid];
    __syncthreads();
    for (int off = 1; off < BRANGE; off <<= 1) {
        int x = (tid < BRANGE && tid >= off) ? excl[tid - off] : 0;
        __syncthreads();
        if (tid < BRANGE) excl[tid] += x;
        __syncthreads();
    }
    if (tid < BRANGE) {
        int e_ = excl[tid] - hist[tid];      // exclusive
        cur[tid] = e_;
        int g = base + tid;
        if (g < N) {
            rp[(size_t)t * (N + 1) + g] = bstart + e_;
            dinv[(size_t)t * N + g] = rsqrtf(1.0f + (float)hist[tid]);
        }
    }
    __syncthreads();

    int* so = srcs + (size_t)t * E + bstart;
    for (int i = tid; i < cnt; i += 256) {
        uint32_t v = eL[i];
        int slot = atomicAdd(&cur[v >> 17], 1);
        so[slot] = (int)(v & 0x1FFFF);
    }
}

// ===========================================================================
// fp32 GEMM: H[N x BN] = act(X[N x 128]) @ W[128 x BN]   (unchanged)
// ===========================================================================
template<int BN, int TN, bool RELU>
__global__ __launch_bounds__(256) void gemm_kernel(
    const float* __restrict__ X, const float* __restrict__ W,
    float* __restrict__ H, int N)
{
    constexpr int BM = 128;
    constexpr int K  = 128;
    constexpr int TM = 8;
    constexpr int XS_STRIDE = K + 4;

    __shared__ float Xs[BM * XS_STRIDE];
    __shared__ float Ws[K * BN];

    const int tid  = threadIdx.x;
    const int row0 = blockIdx.x * BM;

    constexpr int XV = BM * K / 4;
    for (int i = tid; i < XV; i += 256) {
        int r  = i >> 5;
        int c4 = i & 31;
        float4 v = make_float4(0.f, 0.f, 0.f, 0.f);
        int gr = row0 + r;
        if (gr < N) {
            v = reinterpret_cast<const float4*>(X + (size_t)gr * K)[c4];
            if (RELU) {
                v.x = fmaxf(v.x, 0.f); v.y = fmaxf(v.y, 0.f);
                v.z = fmaxf(v.z, 0.f); v.w = fmaxf(v.w, 0.f);
            }
        }
        *reinterpret_cast<float4*>(&Xs[r * XS_STRIDE + c4 * 4]) = v;
    }
    constexpr int WV = K * BN / 4;
    {
        const float4* W4  = reinterpret_cast<const float4*>(W);
        float4*       Ws4 = reinterpret_cast<float4*>(Ws);
        for (int i = tid; i < WV; i += 256) Ws4[i] = W4[i];
    }
    __syncthreads();

    const int tx = tid & 15;
    const int ty = tid >> 4;

    float acc[TM][TN];
#pragma unroll
    for (int m = 0; m < TM; ++m)
#pragma unroll
        for (int n = 0; n < TN; ++n) acc[m][n] = 0.f;

#pragma unroll 4
    for (int k = 0; k < K; ++k) {
        float a[TM];
#pragma unroll
        for (int m = 0; m < TM; ++m)
            a[m] = Xs[(ty + m * 16) * XS_STRIDE + k];
        float b[TN];
        const float* wrow = &Ws[k * BN + tx * TN];
#pragma unroll
        for (int n = 0; n < TN; n += 4) {
            float4 bv = *reinterpret_cast<const float4*>(wrow + n);
            b[n] = bv.x; b[n + 1] = bv.y; b[n + 2] = bv.z; b[n + 3] = bv.w;
        }
#pragma unroll
        for (int m = 0; m < TM; ++m)
#pragma unroll
            for (int n = 0; n < TN; ++n)
                acc[m][n] = fmaf(a[m], b[n], acc[m][n]);
    }

#pragma unroll
    for (int m = 0; m < TM; ++m) {
        int gr = row0 + ty + m * 16;
        if (gr < N) {
            float* orow = H + (size_t)gr * BN + tx * TN;
#pragma unroll
            for (int n = 0; n < TN; n += 4) {
                *reinterpret_cast<float4*>(orow + n) =
                    make_float4(acc[m][n], acc[m][n + 1], acc[m][n + 2], acc[m][n + 3]);
            }
        }
    }
}

// ===========================================================================
// CSR gather: one wave per dst node; lane owns 2 feature cols. (unchanged)
// ===========================================================================
template<int F>
__global__ __launch_bounds__(256) void gather_csr_kernel(
    float* __restrict__ out, const float* __restrict__ H,
    const float* __restrict__ dinv, const int* __restrict__ rp,
    const int* __restrict__ srcs, const float* __restrict__ bias,
    int N, int accum)
{
    int wave = threadIdx.x >> 6;
    int lane = threadIdx.x & 63;
    int i = blockIdx.x * 4 + wave;
    if (i >= N) return;
    int c = lane * 2;
    if (c >= F) return;

    int beg = rp[i], end = rp[i + 1];
    float ax = 0.f, ay = 0.f;
    int j = beg;
    for (; j + 4 <= end; j += 4) {
        int s0 = srcs[j], s1 = srcs[j + 1], s2 = srcs[j + 2], s3 = srcs[j + 3];
        float d0 = dinv[s0], d1 = dinv[s1], d2 = dinv[s2], d3 = dinv[s3];
        float2 h0 = *reinterpret_cast<const float2*>(H + (size_t)s0 * F + c);
        float2 h1 = *reinterpret_cast<const float2*>(H + (size_t)s1 * F + c);
        float2 h2 = *reinterpret_cast<const float2*>(H + (size_t)s2 * F + c);
        float2 h3 = *reinterpret_cast<const float2*>(H + (size_t)s3 * F + c);
        ax = fmaf(h0.x, d0, fmaf(h1.x, d1, fmaf(h2.x, d2, fmaf(h3.x, d3, ax))));
        ay = fmaf(h0.y, d0, fmaf(h1.y, d1, fmaf(h2.y, d2, fmaf(h3.y, d3, ay))));
    }
    for (; j < end; ++j) {
        int s = srcs[j];
        float d = dinv[s];
        float2 h = *reinterpret_cast<const float2*>(H + (size_t)s * F + c);
        ax = fmaf(h.x, d, ax);
        ay = fmaf(h.y, d, ay);
    }
    float di = dinv[i];
    float2 hs = *reinterpret_cast<const float2*>(H + (size_t)i * F + c);
    float2 bv = *reinterpret_cast<const float2*>(bias + c);
    float rx = (ax * di + hs.x * di * di + bv.x) * (1.0f / 3.0f);
    float ry = (ay * di + hs.y * di * di + bv.y) * (1.0f / 3.0f);
    float* op = out + (size_t)i * F + c;
    if (accum) { rx += op[0]; ry += op[1]; }
    *reinterpret_cast<float2*>(op) = make_float2(rx, ry);
}

// ===========================================================================
extern "C" void kernel_launch(void* const* d_in, const int* in_sizes, int n_in,
                              void* d_out, int out_size, void* d_ws, size_t ws_size,
                              hipStream_t stream) {
    const float* x     = (const float*)d_in[0];
    const int*   edges = (const int*)  d_in[1];
    const float* W1    = (const float*)d_in[2];
    const float* b1    = (const float*)d_in[3];
    const float* W2    = (const float*)d_in[4];
    const float* b2    = (const float*)d_in[5];
    float* out = (float*)d_out;

    const int N = in_sizes[0] / F_IN;
    const int E = in_sizes[1] / (T_REL * 2);
    const int KB = (N + BRANGE - 1) >> BSHIFT;      // buckets per relation

    // ---- workspace layout (256B-aligned chunks) ----
    auto align256 = [](size_t x) { return (x + 255) & ~(size_t)255; };
    char* p = (char*)d_ws;
    float* dinv    = (float*)p;  p += align256((size_t)T_REL * N * 4);
    int*   rp      = (int*)p;    p += align256((size_t)T_REL * (N + 1) * 4);
    int*   bcnt    = (int*)p;    p += align256((size_t)T_REL * KB * 4);
    int*   bstart  = (int*)p;    p += align256((size_t)T_REL * (KB + 1) * 4);
    int*   srcs    = (int*)p;    p += align256((size_t)T_REL * E * 4);
    float* Hbuf    = (float*)p;  p += align256((size_t)N * F_HID * 4);
    float* h1      = (float*)p;
    // binned (29 MB) overlays Hbuf (51 MB): dead before first GEMM writes Hbuf
    uint32_t* binned = (uint32_t*)Hbuf;

    const int B = 256;

    // ---- CSR build: bin -> scan -> per-bucket sort (also emits rp, dinv) ----
    hipMemsetAsync(bcnt, 0, (size_t)T_REL * KB * sizeof(int), stream);
    {
        dim3 g((E + CHUNK_E - 1) / CHUNK_E, T_REL);
        bin_kernel<<<g, B, 0, stream>>>(bcnt, binned, edges, E, KB);
    }
    bucket_scan_kernel<<<T_REL, 1024, 0, stream>>>(bcnt, bstart, rp, KB, N, E);
    {
        dim3 g(KB, T_REL);
        bucket_sort_kernel<<<g, B, 0, stream>>>(bcnt, bstart, binned, srcs,
                                                rp, dinv, KB, N, E);
    }

    const int gather_grid = (N + 3) / 4;

    // ---- layer 1: h1 = mean_t( GCNConv(x@W1[t]) + b1[t] ) ----
    for (int t = 0; t < T_REL; ++t) {
        gemm_kernel<128, 8, false><<<(N + 127) / 128, 256, 0, stream>>>(
            x, W1 + (size_t)t * F_IN * F_HID, Hbuf, N);
        gather_csr_kernel<128><<<gather_grid, 256, 0, stream>>>(
            h1, Hbuf, dinv + (size_t)t * N, rp + (size_t)t * (N + 1),
            srcs + (size_t)t * E, b1 + (size_t)t * F_HID, N, t > 0 ? 1 : 0);
    }

    // ---- layer 2: out = mean_t( GCNConv(relu(h1)@W2[t]) + b2[t] ) ----
    for (int t = 0; t < T_REL; ++t) {
        gemm_kernel<64, 4, true><<<(N + 127) / 128, 256, 0, stream>>>(
            h1, W2 + (size_t)t * F_HID * F_OUT, Hbuf, N);
        gather_csr_kernel<64><<<gather_grid, 256, 0, stream>>>(
            out, Hbuf, dinv + (size_t)t * N, rp + (size_t)t * (N + 1),
            srcs + (size_t)t * E, b2 + (size_t)t * F_OUT, N, t > 0 ? 1 : 0);
    }
}

// Round 5
// 1080.600 us; speedup vs baseline: 2.0098x; 1.2816x over previous
//
#include <hip/hip_runtime.h>
#include <hip/hip_fp16.h>
#include <stdint.h>

#define T_REL 3
#define F_IN  128
#define F_HID 128
#define F_OUT 64

#define BSHIFT 7                 // 128 dst nodes per bucket
#define BRANGE (1 << BSHIFT)
#define BCAP   3072              // mean 2048, sigma ~45 -> 22 sigma headroom
#define KB_MAX 1024
#define CHUNK_E 4096             // edges per bin block (391 blocks/relation)

// ===========================================================================
// Bucketed counting-sort CSR build.
// ===========================================================================
__global__ __launch_bounds__(256) void bin_kernel(
    int* __restrict__ bucketCount, uint32_t* __restrict__ binned,
    const int* __restrict__ edges, int E, int KB)
{
    int t = blockIdx.y;
    int tid = threadIdx.x;
    int e0 = blockIdx.x * CHUNK_E;
    int eend = min(e0 + CHUNK_E, E);

    __shared__ int hist[KB_MAX];
    __shared__ int base[KB_MAX];

    for (int b = tid; b < KB; b += 256) hist[b] = 0;
    __syncthreads();

    const int* srcA = edges + (size_t)(t * 2) * E;
    const int* dstA = edges + (size_t)(t * 2 + 1) * E;

    // pass 1: LDS histogram of buckets
    for (int i = e0 + tid; i < eend; i += 256)
        atomicAdd(&hist[dstA[i] >> BSHIFT], 1);
    __syncthreads();

    // reserve contiguous ranges: one global atomic per (block,bucket)
    for (int b = tid; b < KB; b += 256) {
        int h = hist[b];
        base[b] = h ? atomicAdd(&bucketCount[t * KB + b], h) : 0;
        hist[b] = 0;                        // reuse as in-range cursor
    }
    __syncthreads();

    // pass 2: write packed (local_dst<<17 | src) into reserved dense ranges
    for (int i = e0 + tid; i < eend; i += 256) {
        int s = srcA[i];
        int d = dstA[i];
        int b = d >> BSHIFT;
        int pos = base[b] + atomicAdd(&hist[b], 1);
        if (pos < BCAP)
            binned[((size_t)t * KB + b) * BCAP + pos] =
                ((uint32_t)(d & (BRANGE - 1)) << 17) | (uint32_t)s;
    }
}

// exclusive scan of bucket counts (one block per relation, KB <= 1024)
__global__ __launch_bounds__(1024) void bucket_scan_kernel(
    const int* __restrict__ bucketCount, int* __restrict__ bucketStart,
    int* __restrict__ rp, int KB, int N, int E)
{
    int t = blockIdx.x;
    int tid = threadIdx.x;
    __shared__ int sh[1024];
    int v = (tid < KB) ? bucketCount[t * KB + tid] : 0;
    sh[tid] = v;
    __syncthreads();
    for (int off = 1; off < 1024; off <<= 1) {
        int x = (tid >= off) ? sh[tid - off] : 0;
        __syncthreads();
        sh[tid] += x;
        __syncthreads();
    }
    if (tid < KB) bucketStart[t * (KB + 1) + tid] = sh[tid] - v;
    if (tid == 0) {
        bucketStart[t * (KB + 1) + KB] = E;
        rp[(size_t)t * (N + 1) + N] = E;
    }
}

// per-bucket: LDS histogram (=> rp, dinv) + LDS cursor scatter => dense srcs
__global__ __launch_bounds__(256) void bucket_sort_kernel(
    const int* __restrict__ bucketCount, const int* __restrict__ bucketStart,
    const uint32_t* __restrict__ binned, int* __restrict__ srcs,
    int* __restrict__ rp, float* __restrict__ dinv,
    int KB, int N, int E)
{
    int t = blockIdx.y, b = blockIdx.x, tid = threadIdx.x;
    int base = b << BSHIFT;
    int cnt = bucketCount[t * KB + b];
    if (cnt > BCAP) cnt = BCAP;
    int bstart = bucketStart[t * (KB + 1) + b];

    __shared__ uint32_t eL[BCAP];
    __shared__ int hist[BRANGE];
    __shared__ int excl[BRANGE];
    __shared__ int cur[BRANGE];

    if (tid < BRANGE) hist[tid] = 0;
    __syncthreads();

    const uint32_t* bin = binned + ((size_t)t * KB + b) * BCAP;
    for (int i = tid; i < cnt; i += 256) {
        uint32_t v = bin[i];
        eL[i] = v;
        atomicAdd(&hist[v >> 17], 1);
    }
    __syncthreads();

    if (tid < BRANGE) excl[tid] = hist[tid];
    __syncthreads();
    for (int off = 1; off < BRANGE; off <<= 1) {
        int x = (tid < BRANGE && tid >= off) ? excl[tid - off] : 0;
        __syncthreads();
        if (tid < BRANGE) excl[tid] += x;
        __syncthreads();
    }
    if (tid < BRANGE) {
        int e_ = excl[tid] - hist[tid];      // exclusive
        cur[tid] = e_;
        int g = base + tid;
        if (g < N) {
            rp[(size_t)t * (N + 1) + g] = bstart + e_;
            dinv[(size_t)t * N + g] = rsqrtf(1.0f + (float)hist[tid]);
        }
    }
    __syncthreads();

    int* so = srcs + (size_t)t * E + bstart;
    for (int i = tid; i < cnt; i += 256) {
        uint32_t v = eL[i];
        int slot = atomicAdd(&cur[v >> 17], 1);
        so[slot] = (int)(v & 0x1FFFF);
    }
}

// ===========================================================================
// fp32 GEMM: H[N x BN] = act(X[N x 128]) @ W[128 x BN], fp16 output.
// ===========================================================================
template<int BN, int TN, bool RELU>
__global__ __launch_bounds__(256) void gemm_kernel(
    const float* __restrict__ X, const float* __restrict__ W,
    __half* __restrict__ H, int N)
{
    constexpr int BM = 128;
    constexpr int K  = 128;
    constexpr int TM = 8;
    constexpr int XS_STRIDE = K + 4;

    __shared__ float Xs[BM * XS_STRIDE];
    __shared__ float Ws[K * BN];

    const int tid  = threadIdx.x;
    const int row0 = blockIdx.x * BM;

    constexpr int XV = BM * K / 4;
    for (int i = tid; i < XV; i += 256) {
        int r  = i >> 5;
        int c4 = i & 31;
        float4 v = make_float4(0.f, 0.f, 0.f, 0.f);
        int gr = row0 + r;
        if (gr < N) {
            v = reinterpret_cast<const float4*>(X + (size_t)gr * K)[c4];
            if (RELU) {
                v.x = fmaxf(v.x, 0.f); v.y = fmaxf(v.y, 0.f);
                v.z = fmaxf(v.z, 0.f); v.w = fmaxf(v.w, 0.f);
            }
        }
        *reinterpret_cast<float4*>(&Xs[r * XS_STRIDE + c4 * 4]) = v;
    }
    constexpr int WV = K * BN / 4;
    {
        const float4* W4  = reinterpret_cast<const float4*>(W);
        float4*       Ws4 = reinterpret_cast<float4*>(Ws);
        for (int i = tid; i < WV; i += 256) Ws4[i] = W4[i];
    }
    __syncthreads();

    const int tx = tid & 15;
    const int ty = tid >> 4;

    float acc[TM][TN];
#pragma unroll
    for (int m = 0; m < TM; ++m)
#pragma unroll
        for (int n = 0; n < TN; ++n) acc[m][n] = 0.f;

#pragma unroll 4
    for (int k = 0; k < K; ++k) {
        float a[TM];
#pragma unroll
        for (int m = 0; m < TM; ++m)
            a[m] = Xs[(ty + m * 16) * XS_STRIDE + k];
        float b[TN];
        const float* wrow = &Ws[k * BN + tx * TN];
#pragma unroll
        for (int n = 0; n < TN; n += 4) {
            float4 bv = *reinterpret_cast<const float4*>(wrow + n);
            b[n] = bv.x; b[n + 1] = bv.y; b[n + 2] = bv.z; b[n + 3] = bv.w;
        }
#pragma unroll
        for (int m = 0; m < TM; ++m)
#pragma unroll
            for (int n = 0; n < TN; ++n)
                acc[m][n] = fmaf(a[m], b[n], acc[m][n]);
    }

#pragma unroll
    for (int m = 0; m < TM; ++m) {
        int gr = row0 + ty + m * 16;
        if (gr < N) {
            __half* orow = H + (size_t)gr * BN + tx * TN;
            __half2 pk[TN / 2];
#pragma unroll
            for (int n = 0; n < TN; n += 2)
                pk[n / 2] = __floats2half2_rn(acc[m][n], acc[m][n + 1]);
            if constexpr (TN == 8)
                *reinterpret_cast<float4*>(orow) = *reinterpret_cast<float4*>(pk);
            else
                *reinterpret_cast<float2*>(orow) = *reinterpret_cast<float2*>(pk);
        }
    }
}

// ===========================================================================
// CSR gather from fp16 H, fp32 accumulate. F=128: 1 node/wave (lane owns 2
// cols). F=64: 2 nodes/wave (half-wave per node) so no idle lanes.
// ===========================================================================
template<int F>
__global__ __launch_bounds__(256) void gather_csr_kernel(
    float* __restrict__ out, const __half* __restrict__ H,
    const float* __restrict__ dinv, const int* __restrict__ rp,
    const int* __restrict__ srcs, const float* __restrict__ bias,
    int N, int accum)
{
    constexpr int NPW = (F == 64) ? 2 : 1;   // nodes per wave
    int wave = threadIdx.x >> 6;
    int lane = threadIdx.x & 63;
    int sub  = (NPW == 2) ? (lane >> 5) : 0;
    int lsub = (NPW == 2) ? (lane & 31) : lane;
    int i = (blockIdx.x * 4 + wave) * NPW + sub;
    if (i >= N) return;
    int c = lsub * 2;

    int beg = rp[i], end = rp[i + 1];
    float ax = 0.f, ay = 0.f;
    int j = beg;
    for (; j + 4 <= end; j += 4) {
        int s0 = srcs[j], s1 = srcs[j + 1], s2 = srcs[j + 2], s3 = srcs[j + 3];
        float d0 = dinv[s0], d1 = dinv[s1], d2 = dinv[s2], d3 = dinv[s3];
        float2 h0 = __half22float2(*reinterpret_cast<const __half2*>(H + (size_t)s0 * F + c));
        float2 h1 = __half22float2(*reinterpret_cast<const __half2*>(H + (size_t)s1 * F + c));
        float2 h2 = __half22float2(*reinterpret_cast<const __half2*>(H + (size_t)s2 * F + c));
        float2 h3 = __half22float2(*reinterpret_cast<const __half2*>(H + (size_t)s3 * F + c));
        ax = fmaf(h0.x, d0, fmaf(h1.x, d1, fmaf(h2.x, d2, fmaf(h3.x, d3, ax))));
        ay = fmaf(h0.y, d0, fmaf(h1.y, d1, fmaf(h2.y, d2, fmaf(h3.y, d3, ay))));
    }
    for (; j < end; ++j) {
        int s = srcs[j];
        float d = dinv[s];
        float2 h = __half22float2(*reinterpret_cast<const __half2*>(H + (size_t)s * F + c));
        ax = fmaf(h.x, d, ax);
        ay = fmaf(h.y, d, ay);
    }
    float di = dinv[i];
    float2 hs = __half22float2(*reinterpret_cast<const __half2*>(H + (size_t)i * F + c));
    float2 bv = *reinterpret_cast<const float2*>(bias + c);
    float rx = (ax * di + hs.x * di * di + bv.x) * (1.0f / 3.0f);
    float ry = (ay * di + hs.y * di * di + bv.y) * (1.0f / 3.0f);
    float* op = out + (size_t)i * F + c;
    if (accum) { rx += op[0]; ry += op[1]; }
    *reinterpret_cast<float2*>(op) = make_float2(rx, ry);
}

// ===========================================================================
extern "C" void kernel_launch(void* const* d_in, const int* in_sizes, int n_in,
                              void* d_out, int out_size, void* d_ws, size_t ws_size,
                              hipStream_t stream) {
    const float* x     = (const float*)d_in[0];
    const int*   edges = (const int*)  d_in[1];
    const float* W1    = (const float*)d_in[2];
    const float* b1    = (const float*)d_in[3];
    const float* W2    = (const float*)d_in[4];
    const float* b2    = (const float*)d_in[5];
    float* out = (float*)d_out;

    const int N = in_sizes[0] / F_IN;
    const int E = in_sizes[1] / (T_REL * 2);
    const int KB = (N + BRANGE - 1) >> BSHIFT;      // buckets per relation

    // ---- workspace layout (256B-aligned chunks) ----
    auto align256 = [](size_t x) { return (x + 255) & ~(size_t)255; };
    char* p = (char*)d_ws;
    float*  dinv   = (float*)p;  p += align256((size_t)T_REL * N * 4);
    int*    rp     = (int*)p;    p += align256((size_t)T_REL * (N + 1) * 4);
    int*    bcnt   = (int*)p;    p += align256((size_t)T_REL * KB * 4);
    int*    bstart = (int*)p;    p += align256((size_t)T_REL * (KB + 1) * 4);
    int*    srcs   = (int*)p;    p += align256((size_t)T_REL * E * 4);
    __half* Hbuf   = (__half*)p; p += align256((size_t)N * F_HID * 2);
    float*  h1     = (float*)p;
    // binned (28.8 MB) overlays Hbuf(25.6 MB fp16)+h1: both dead until after
    // bucket_sort consumes binned (GEMM/gather run strictly later in-stream)
    uint32_t* binned = (uint32_t*)Hbuf;

    const int B = 256;

    // ---- CSR build: bin -> scan -> per-bucket sort (also emits rp, dinv) ----
    hipMemsetAsync(bcnt, 0, (size_t)T_REL * KB * sizeof(int), stream);
    {
        dim3 g((E + CHUNK_E - 1) / CHUNK_E, T_REL);
        bin_kernel<<<g, B, 0, stream>>>(bcnt, binned, edges, E, KB);
    }
    bucket_scan_kernel<<<T_REL, 1024, 0, stream>>>(bcnt, bstart, rp, KB, N, E);
    {
        dim3 g(KB, T_REL);
        bucket_sort_kernel<<<g, B, 0, stream>>>(bcnt, bstart, binned, srcs,
                                                rp, dinv, KB, N, E);
    }

    // ---- layer 1: h1 = mean_t( GCNConv(x@W1[t]) + b1[t] ) ----
    for (int t = 0; t < T_REL; ++t) {
        gemm_kernel<128, 8, false><<<(N + 127) / 128, 256, 0, stream>>>(
            x, W1 + (size_t)t * F_IN * F_HID, Hbuf, N);
        gather_csr_kernel<128><<<(N + 3) / 4, 256, 0, stream>>>(
            h1, Hbuf, dinv + (size_t)t * N, rp + (size_t)t * (N + 1),
            srcs + (size_t)t * E, b1 + (size_t)t * F_HID, N, t > 0 ? 1 : 0);
    }

    // ---- layer 2: out = mean_t( GCNConv(relu(h1)@W2[t]) + b2[t] ) ----
    for (int t = 0; t < T_REL; ++t) {
        gemm_kernel<64, 4, true><<<(N + 127) / 128, 256, 0, stream>>>(
            h1, W2 + (size_t)t * F_HID * F_OUT, Hbuf, N);
        gather_csr_kernel<64><<<(N + 7) / 8, 256, 0, stream>>>(
            out, Hbuf, dinv + (size_t)t * N, rp + (size_t)t * (N + 1),
            srcs + (size_t)t * E, b2 + (size_t)t * F_OUT, N, t > 0 ? 1 : 0);
    }
}

// Round 6
// 812.278 us; speedup vs baseline: 2.6738x; 1.3303x over previous
//
#include <hip/hip_runtime.h>
#include <hip/hip_fp16.h>
#include <stdint.h>

#define T_REL 3
#define F_IN  128
#define F_HID 128
#define F_OUT 64

#define BSHIFT 7                 // 128 dst nodes per bucket
#define BRANGE (1 << BSHIFT)
#define BCAP   3072              // mean 2048, sigma ~45 -> 22 sigma headroom
#define KB_MAX 1024
#define CHUNK_E 4096             // edges per bin block
#define NB_MAX 512

typedef _Float16 f16x8 __attribute__((ext_vector_type(8)));
typedef float    f32x4v __attribute__((ext_vector_type(4)));

// ===========================================================================
// CSR build, all-dense writes, no global atomics.
// A) bin_dense: block-local counting sort -> contiguous block-major segment
// B) bucket_scan: column-sum of [NB][KB] counts (coalesced) + scan
// C) bucket_gather_sort: gather segments -> LDS -> per-node sort -> dense srcs
// ===========================================================================
__global__ __launch_bounds__(256) void bin_dense_kernel(
    int* __restrict__ bHist, int* __restrict__ lStart,
    uint32_t* __restrict__ binned, const int* __restrict__ edges,
    int E, int KB, int NB)
{
    int t = blockIdx.y, blk = blockIdx.x, tid = threadIdx.x;
    int e0 = blk * CHUNK_E;
    int cnt = min(CHUNK_E, E - e0);

    __shared__ int hist[KB_MAX];
    __shared__ int cursor[KB_MAX];
    __shared__ int sh[256];
    __shared__ uint32_t obuf[CHUNK_E];

    for (int b = tid; b < KB_MAX; b += 256) hist[b] = 0;
    __syncthreads();

    const int* srcA = edges + (size_t)(t * 2) * E;
    const int* dstA = edges + (size_t)(t * 2 + 1) * E;

    uint32_t pk[16]; int bk[16];
#pragma unroll
    for (int r = 0; r < 16; ++r) {
        int i = r * 256 + tid;
        if (i < cnt) {
            int s = srcA[e0 + i], d = dstA[e0 + i];
            bk[r] = d >> BSHIFT;
            pk[r] = ((uint32_t)(d & (BRANGE - 1)) << 17) | (uint32_t)s;
            atomicAdd(&hist[bk[r]], 1);
        } else bk[r] = -1;
    }
    __syncthreads();

    // exclusive scan of hist[0..1024) -> cursor (4 entries/thread)
    int b4 = tid * 4;
    int v0 = hist[b4], v1 = hist[b4 + 1], v2 = hist[b4 + 2], v3 = hist[b4 + 3];
    sh[tid] = v0 + v1 + v2 + v3;
    __syncthreads();
    for (int off = 1; off < 256; off <<= 1) {
        int x = (tid >= off) ? sh[tid - off] : 0;
        __syncthreads(); sh[tid] += x; __syncthreads();
    }
    int texcl = tid ? sh[tid - 1] : 0;
    cursor[b4] = texcl;
    cursor[b4 + 1] = texcl + v0;
    cursor[b4 + 2] = texcl + v0 + v1;
    cursor[b4 + 3] = texcl + v0 + v1 + v2;
    __syncthreads();

    // dense per-block rows: counts + local offsets (coalesced writes)
    int* bh = bHist + ((size_t)t * NB + blk) * KB;
    int* ls = lStart + ((size_t)t * NB + blk) * KB;
    for (int b = tid; b < KB; b += 256) { bh[b] = hist[b]; ls[b] = cursor[b]; }
    __syncthreads();

    // place edges into LDS staging at sorted positions
#pragma unroll
    for (int r = 0; r < 16; ++r) {
        if (bk[r] >= 0) {
            int pos = atomicAdd(&cursor[bk[r]], 1);
            obuf[pos] = pk[r];
        }
    }
    __syncthreads();

    // dense dump: one writer per line, sequential
    for (int i = tid; i < cnt; i += 256)
        binned[(size_t)t * E + e0 + i] = obuf[i];
}

__global__ __launch_bounds__(1024) void bucket_scan_kernel(
    const int* __restrict__ bHist, int* __restrict__ bucketStart,
    int* __restrict__ rp, int KB, int NB, int N, int E)
{
    int t = blockIdx.x, tid = threadIdx.x;
    __shared__ int sh[1024];
    int v = 0;
    if (tid < KB) {
        const int* col = bHist + (size_t)t * NB * KB + tid;
        for (int r = 0; r < NB; ++r) v += col[(size_t)r * KB];
    }
    sh[tid] = v;
    __syncthreads();
    for (int off = 1; off < 1024; off <<= 1) {
        int x = (tid >= off) ? sh[tid - off] : 0;
        __syncthreads(); sh[tid] += x; __syncthreads();
    }
    if (tid < KB) bucketStart[t * (KB + 1) + tid] = sh[tid] - v;
    if (tid == 0) {
        bucketStart[t * (KB + 1) + KB] = E;
        rp[(size_t)t * (N + 1) + N] = E;
    }
}

__global__ __launch_bounds__(256) void bucket_gather_sort_kernel(
    const int* __restrict__ bHist, const int* __restrict__ lStart,
    const int* __restrict__ bucketStart, const uint32_t* __restrict__ binned,
    int* __restrict__ srcs, int* __restrict__ rp, float* __restrict__ dinv,
    int KB, int NB, int N, int E)
{
    int t = blockIdx.y, b = blockIdx.x, tid = threadIdx.x;
    int base = b << BSHIFT;
    int bstart = bucketStart[t * (KB + 1) + b];

    __shared__ uint32_t eL[BCAP];
    __shared__ int bc[NB_MAX], bo[NB_MAX];
    __shared__ int sh[256];
    __shared__ int hist[BRANGE], excl[BRANGE], cur[BRANGE];

    for (int r = tid; r < NB_MAX; r += 256) bc[r] = 0;
    if (tid < BRANGE) hist[tid] = 0;
    __syncthreads();
    for (int r = tid; r < NB; r += 256)
        bc[r] = bHist[((size_t)t * NB + r) * KB + b];
    __syncthreads();

    // scan bc[0..512) (2/thread) -> per-segment offset into eL
    int i2 = tid * 2;
    int u0 = bc[i2], u1 = bc[i2 + 1];
    sh[tid] = u0 + u1;
    __syncthreads();
    for (int off = 1; off < 256; off <<= 1) {
        int x = (tid >= off) ? sh[tid - off] : 0;
        __syncthreads(); sh[tid] += x; __syncthreads();
    }
    int te = tid ? sh[tid - 1] : 0;
    bo[i2] = te; bo[i2 + 1] = te + u0;
    __syncthreads();
    int cnt = sh[255]; if (cnt > BCAP) cnt = BCAP;

    // gather this bucket's runs from all block segments; hist on the fly
    for (int r = tid; r < NB; r += 256) {
        int c = bc[r];
        if (!c) continue;
        int off = bo[r];
        const uint32_t* sp = binned + (size_t)t * E + (size_t)r * CHUNK_E
                           + lStart[((size_t)t * NB + r) * KB + b];
        for (int i = 0; i < c; ++i) {
            int p = off + i;
            if (p < BCAP) {
                uint32_t v = sp[i];
                eL[p] = v;
                atomicAdd(&hist[v >> 17], 1);
            }
        }
    }
    __syncthreads();

    // scan 128-node histogram -> per-node CSR offsets + dinv
    if (tid < BRANGE) excl[tid] = hist[tid];
    __syncthreads();
    for (int off = 1; off < BRANGE; off <<= 1) {
        int x = (tid < BRANGE && tid >= off) ? excl[tid - off] : 0;
        __syncthreads();
        if (tid < BRANGE) excl[tid] += x;
        __syncthreads();
    }
    if (tid < BRANGE) {
        int e_ = excl[tid] - hist[tid];
        cur[tid] = e_;
        int g = base + tid;
        if (g < N) {
            rp[(size_t)t * (N + 1) + g] = bstart + e_;
            dinv[(size_t)t * N + g] = rsqrtf(1.0f + (float)hist[tid]);
        }
    }
    __syncthreads();

    int* so = srcs + (size_t)t * E + bstart;
    for (int i = tid; i < cnt; i += 256) {
        uint32_t v = eL[i];
        int slot = atomicAdd(&cur[v >> 17], 1);
        so[slot] = (int)(v & 0x1FFFF);
    }
}

// ===========================================================================
// MFMA fp16 GEMM (fp32 accumulate): H[N x BN] = act(X[N x 128]) @ W[128 x BN]
// Block: 64 rows x BN cols, 4 waves; wave w owns 16 rows, loops col-tiles.
// v_mfma_f32_16x16x32_f16: A[m=lane&15][k=(lane>>4)*8+j],
// B[k=(lane>>4)*8+j][n=lane&15], D: row=(lane>>4)*4+reg, col=lane&15.
// ===========================================================================
template<int BN, bool RELU>
__global__ __launch_bounds__(256) void mfma_gemm_kernel(
    const float* __restrict__ X, const float* __restrict__ W,
    __half* __restrict__ H, int N)
{
    constexpr int BM = 64, K = 128;
    constexpr int XST = K + 8;               // half stride 136: 2-way (free) LDS
    constexpr int WST = K + 8;
    constexpr int LB = (BN == 128) ? 7 : 6;

    __shared__ _Float16 Xs[BM * XST];
    __shared__ _Float16 Ws[BN * WST];

    int tid = threadIdx.x;
    int row0 = blockIdx.x * BM;

    // stage X (fp32 -> fp16, fused relu for layer 2)
#pragma unroll
    for (int u = 0; u < (BM * K / 4) / 256; ++u) {   // 8 float4 per thread
        int i = u * 256 + tid;
        int r = i >> 5, c4 = i & 31;
        int gr = row0 + r;
        float4 v = make_float4(0.f, 0.f, 0.f, 0.f);
        if (gr < N) v = reinterpret_cast<const float4*>(X)[(size_t)gr * (K / 4) + c4];
        if (RELU) {
            v.x = fmaxf(v.x, 0.f); v.y = fmaxf(v.y, 0.f);
            v.z = fmaxf(v.z, 0.f); v.w = fmaxf(v.w, 0.f);
        }
        _Float16* xp = &Xs[r * XST + c4 * 4];
        xp[0] = (_Float16)v.x; xp[1] = (_Float16)v.y;
        xp[2] = (_Float16)v.z; xp[3] = (_Float16)v.w;
    }
    // stage W transposed: Ws[n][k] = W[k][n]
    for (int idx = tid; idx < K * BN; idx += 256) {
        int k = idx >> LB, n = idx & (BN - 1);
        Ws[n * WST + k] = (_Float16)W[idx];
    }
    __syncthreads();

    int wv = tid >> 6, lane = tid & 63, quad = lane >> 4, lr = lane & 15;
    int rw = wv * 16;

    f16x8 a[4];
#pragma unroll
    for (int kk = 0; kk < 4; ++kk)
        a[kk] = *reinterpret_cast<const f16x8*>(&Xs[(rw + lr) * XST + quad * 8 + kk * 32]);

#pragma unroll
    for (int ct = 0; ct < BN / 16; ++ct) {
        f32x4v acc = {0.f, 0.f, 0.f, 0.f};
#pragma unroll
        for (int kk = 0; kk < 4; ++kk) {
            f16x8 bf = *reinterpret_cast<const f16x8*>(&Ws[(ct * 16 + lr) * WST + quad * 8 + kk * 32]);
            acc = __builtin_amdgcn_mfma_f32_16x16x32_f16(a[kk], bf, acc, 0, 0, 0);
        }
#pragma unroll
        for (int reg = 0; reg < 4; ++reg) {
            int gr = row0 + rw + quad * 4 + reg;
            if (gr < N) H[(size_t)gr * BN + ct * 16 + lr] = (__half)acc[reg];
        }
    }
}

// ===========================================================================
// CSR gather from fp16 H, fp32 accumulate. F=128: 1 node/wave; F=64: 2/wave.
// ===========================================================================
template<int F>
__global__ __launch_bounds__(256) void gather_csr_kernel(
    float* __restrict__ out, const __half* __restrict__ H,
    const float* __restrict__ dinv, const int* __restrict__ rp,
    const int* __restrict__ srcs, const float* __restrict__ bias,
    int N, int accum)
{
    constexpr int NPW = (F == 64) ? 2 : 1;
    int wave = threadIdx.x >> 6;
    int lane = threadIdx.x & 63;
    int sub  = (NPW == 2) ? (lane >> 5) : 0;
    int lsub = (NPW == 2) ? (lane & 31) : lane;
    int i = (blockIdx.x * 4 + wave) * NPW + sub;
    if (i >= N) return;
    int c = lsub * 2;

    int beg = rp[i], end = rp[i + 1];
    float ax = 0.f, ay = 0.f;
    int j = beg;
    for (; j + 4 <= end; j += 4) {
        int s0 = srcs[j], s1 = srcs[j + 1], s2 = srcs[j + 2], s3 = srcs[j + 3];
        float d0 = dinv[s0], d1 = dinv[s1], d2 = dinv[s2], d3 = dinv[s3];
        float2 h0 = __half22float2(*reinterpret_cast<const __half2*>(H + (size_t)s0 * F + c));
        float2 h1 = __half22float2(*reinterpret_cast<const __half2*>(H + (size_t)s1 * F + c));
        float2 h2 = __half22float2(*reinterpret_cast<const __half2*>(H + (size_t)s2 * F + c));
        float2 h3 = __half22float2(*reinterpret_cast<const __half2*>(H + (size_t)s3 * F + c));
        ax = fmaf(h0.x, d0, fmaf(h1.x, d1, fmaf(h2.x, d2, fmaf(h3.x, d3, ax))));
        ay = fmaf(h0.y, d0, fmaf(h1.y, d1, fmaf(h2.y, d2, fmaf(h3.y, d3, ay))));
    }
    for (; j < end; ++j) {
        int s = srcs[j];
        float d = dinv[s];
        float2 h = __half22float2(*reinterpret_cast<const __half2*>(H + (size_t)s * F + c));
        ax = fmaf(h.x, d, ax);
        ay = fmaf(h.y, d, ay);
    }
    float di = dinv[i];
    float2 hs = __half22float2(*reinterpret_cast<const __half2*>(H + (size_t)i * F + c));
    float2 bv = *reinterpret_cast<const float2*>(bias + c);
    float rx = (ax * di + hs.x * di * di + bv.x) * (1.0f / 3.0f);
    float ry = (ay * di + hs.y * di * di + bv.y) * (1.0f / 3.0f);
    float* op = out + (size_t)i * F + c;
    if (accum) { rx += op[0]; ry += op[1]; }
    *reinterpret_cast<float2*>(op) = make_float2(rx, ry);
}

// ===========================================================================
extern "C" void kernel_launch(void* const* d_in, const int* in_sizes, int n_in,
                              void* d_out, int out_size, void* d_ws, size_t ws_size,
                              hipStream_t stream) {
    const float* x     = (const float*)d_in[0];
    const int*   edges = (const int*)  d_in[1];
    const float* W1    = (const float*)d_in[2];
    const float* b1    = (const float*)d_in[3];
    const float* W2    = (const float*)d_in[4];
    const float* b2    = (const float*)d_in[5];
    float* out = (float*)d_out;

    const int N  = in_sizes[0] / F_IN;
    const int E  = in_sizes[1] / (T_REL * 2);
    const int KB = (N + BRANGE - 1) >> BSHIFT;       // 782 buckets/relation
    const int NB = (E + CHUNK_E - 1) / CHUNK_E;      // 391 bin blocks/relation

    // ---- workspace layout (256B-aligned chunks) ----
    auto align256 = [](size_t x_) { return (x_ + 255) & ~(size_t)255; };
    char* p = (char*)d_ws;
    float*  dinv   = (float*)p;  p += align256((size_t)T_REL * N * 4);
    int*    rp     = (int*)p;    p += align256((size_t)T_REL * (N + 1) * 4);
    int*    bstart = (int*)p;    p += align256((size_t)T_REL * (KB + 1) * 4);
    int*    bHist  = (int*)p;    p += align256((size_t)T_REL * NB * KB * 4);
    int*    lStart = (int*)p;    p += align256((size_t)T_REL * NB * KB * 4);
    int*    srcs   = (int*)p;    p += align256((size_t)T_REL * E * 4);
    __half* Hbuf   = (__half*)p; p += align256((size_t)N * F_HID * 2);
    float*  h1     = (float*)p;
    // binned (19.2 MB) overlays Hbuf (25.6 MB fp16): binned is fully consumed
    // by bucket_gather_sort before the first GEMM writes Hbuf (in-stream order)
    uint32_t* binned = (uint32_t*)Hbuf;

    // ---- CSR build ----
    {
        dim3 g(NB, T_REL);
        bin_dense_kernel<<<g, 256, 0, stream>>>(bHist, lStart, binned, edges, E, KB, NB);
    }
    bucket_scan_kernel<<<T_REL, 1024, 0, stream>>>(bHist, bstart, rp, KB, NB, N, E);
    {
        dim3 g(KB, T_REL);
        bucket_gather_sort_kernel<<<g, 256, 0, stream>>>(
            bHist, lStart, bstart, binned, srcs, rp, dinv, KB, NB, N, E);
    }

    // ---- layer 1: h1 = mean_t( GCNConv(x@W1[t]) + b1[t] ) ----
    for (int t = 0; t < T_REL; ++t) {
        mfma_gemm_kernel<128, false><<<(N + 63) / 64, 256, 0, stream>>>(
            x, W1 + (size_t)t * F_IN * F_HID, Hbuf, N);
        gather_csr_kernel<128><<<(N + 3) / 4, 256, 0, stream>>>(
            h1, Hbuf, dinv + (size_t)t * N, rp + (size_t)t * (N + 1),
            srcs + (size_t)t * E, b1 + (size_t)t * F_HID, N, t > 0 ? 1 : 0);
    }

    // ---- layer 2: out = mean_t( GCNConv(relu(h1)@W2[t]) + b2[t] ) ----
    for (int t = 0; t < T_REL; ++t) {
        mfma_gemm_kernel<64, true><<<(N + 63) / 64, 256, 0, stream>>>(
            h1, W2 + (size_t)t * F_HID * F_OUT, Hbuf, N);
        gather_csr_kernel<64><<<(N + 7) / 8, 256, 0, stream>>>(
            out, Hbuf, dinv + (size_t)t * N, rp + (size_t)t * (N + 1),
            srcs + (size_t)t * E, b2 + (size_t)t * F_OUT, N, t > 0 ? 1 : 0);
    }
}

// Round 7
// 718.492 us; speedup vs baseline: 3.0228x; 1.1305x over previous
//
#include <hip/hip_runtime.h>
#include <hip/hip_fp16.h>
#include <stdint.h>

#define T_REL 3
#define F_IN  128
#define F_HID 128
#define F_OUT 64

#define BSHIFT 7                 // 128 dst nodes per bucket
#define BRANGE (1 << BSHIFT)
#define BCAP   3072              // mean 2048, sigma ~45 -> 22 sigma headroom
#define KB_MAX 1024
#define CHUNK_E 4096             // edges per bin block
#define NB_MAX 512

typedef _Float16 f16x8 __attribute__((ext_vector_type(8)));
typedef float    f32x4v __attribute__((ext_vector_type(4)));

// ===========================================================================
// CSR build, all-dense writes.
// A) bin_dense: block-local counting sort -> contiguous block-major segment;
//    also folds its histogram into global colSum (391 atomics/address total).
// B) bucket_scan: exclusive scan of colSum[KB] (no column-sum loop anymore)
// C) bucket_gather_sort: gather segments -> LDS -> per-node sort -> dense srcs
// D) coef: coefs[j] = dinv_t[srcs[j]]  (hoists random dinv reads out of gather)
// ===========================================================================
__global__ __launch_bounds__(256) void bin_dense_kernel(
    int* __restrict__ bHist, int* __restrict__ lStart, int* __restrict__ colSum,
    uint32_t* __restrict__ binned, const int* __restrict__ edges,
    int E, int KB, int NB)
{
    int t = blockIdx.y, blk = blockIdx.x, tid = threadIdx.x;
    int e0 = blk * CHUNK_E;
    int cnt = min(CHUNK_E, E - e0);

    __shared__ int hist[KB_MAX];
    __shared__ int cursor[KB_MAX];
    __shared__ int sh[256];
    __shared__ uint32_t obuf[CHUNK_E];

    for (int b = tid; b < KB_MAX; b += 256) hist[b] = 0;
    __syncthreads();

    const int* srcA = edges + (size_t)(t * 2) * E;
    const int* dstA = edges + (size_t)(t * 2 + 1) * E;

    uint32_t pk[16]; int bk[16];
#pragma unroll
    for (int r = 0; r < 16; ++r) {
        int i = r * 256 + tid;
        if (i < cnt) {
            int s = srcA[e0 + i], d = dstA[e0 + i];
            bk[r] = d >> BSHIFT;
            pk[r] = ((uint32_t)(d & (BRANGE - 1)) << 17) | (uint32_t)s;
            atomicAdd(&hist[bk[r]], 1);
        } else bk[r] = -1;
    }
    __syncthreads();

    // exclusive scan of hist[0..1024) -> cursor (4 entries/thread)
    int b4 = tid * 4;
    int v0 = hist[b4], v1 = hist[b4 + 1], v2 = hist[b4 + 2], v3 = hist[b4 + 3];
    sh[tid] = v0 + v1 + v2 + v3;
    __syncthreads();
    for (int off = 1; off < 256; off <<= 1) {
        int x = (tid >= off) ? sh[tid - off] : 0;
        __syncthreads(); sh[tid] += x; __syncthreads();
    }
    int texcl = tid ? sh[tid - 1] : 0;
    cursor[b4] = texcl;
    cursor[b4 + 1] = texcl + v0;
    cursor[b4 + 2] = texcl + v0 + v1;
    cursor[b4 + 3] = texcl + v0 + v1 + v2;
    __syncthreads();

    // dense per-block rows: counts + local offsets; fold into global colSum
    int* bh = bHist + ((size_t)t * NB + blk) * KB;
    int* ls = lStart + ((size_t)t * NB + blk) * KB;
    for (int b = tid; b < KB; b += 256) {
        int h = hist[b];
        bh[b] = h; ls[b] = cursor[b];
        if (h) atomicAdd(&colSum[t * KB + b], h);
    }
    __syncthreads();

    // place edges into LDS staging at sorted positions
#pragma unroll
    for (int r = 0; r < 16; ++r) {
        if (bk[r] >= 0) {
            int pos = atomicAdd(&cursor[bk[r]], 1);
            obuf[pos] = pk[r];
        }
    }
    __syncthreads();

    // dense dump: one writer per line, sequential
    for (int i = tid; i < cnt; i += 256)
        binned[(size_t)t * E + e0 + i] = obuf[i];
}

__global__ __launch_bounds__(1024) void bucket_scan_kernel(
    const int* __restrict__ colSum, int* __restrict__ bucketStart,
    int* __restrict__ rp, int KB, int N, int E)
{
    int t = blockIdx.x, tid = threadIdx.x;
    __shared__ int sh[1024];
    int v = (tid < KB) ? colSum[t * KB + tid] : 0;
    sh[tid] = v;
    __syncthreads();
    for (int off = 1; off < 1024; off <<= 1) {
        int x = (tid >= off) ? sh[tid - off] : 0;
        __syncthreads(); sh[tid] += x; __syncthreads();
    }
    if (tid < KB) bucketStart[t * (KB + 1) + tid] = sh[tid] - v;
    if (tid == 0) {
        bucketStart[t * (KB + 1) + KB] = E;
        rp[(size_t)t * (N + 1) + N] = E;
    }
}

__global__ __launch_bounds__(256) void bucket_gather_sort_kernel(
    const int* __restrict__ bHist, const int* __restrict__ lStart,
    const int* __restrict__ bucketStart, const uint32_t* __restrict__ binned,
    int* __restrict__ srcs, int* __restrict__ rp, float* __restrict__ dinv,
    int KB, int NB, int N, int E)
{
    int t = blockIdx.y, b = blockIdx.x, tid = threadIdx.x;
    int base = b << BSHIFT;
    int bstart = bucketStart[t * (KB + 1) + b];

    __shared__ uint32_t eL[BCAP];
    __shared__ int bc[NB_MAX], bo[NB_MAX];
    __shared__ int sh[256];
    __shared__ int hist[BRANGE], excl[BRANGE], cur[BRANGE];

    for (int r = tid; r < NB_MAX; r += 256) bc[r] = 0;
    if (tid < BRANGE) hist[tid] = 0;
    __syncthreads();
    for (int r = tid; r < NB; r += 256)
        bc[r] = bHist[((size_t)t * NB + r) * KB + b];
    __syncthreads();

    int i2 = tid * 2;
    int u0 = bc[i2], u1 = bc[i2 + 1];
    sh[tid] = u0 + u1;
    __syncthreads();
    for (int off = 1; off < 256; off <<= 1) {
        int x = (tid >= off) ? sh[tid - off] : 0;
        __syncthreads(); sh[tid] += x; __syncthreads();
    }
    int te = tid ? sh[tid - 1] : 0;
    bo[i2] = te; bo[i2 + 1] = te + u0;
    __syncthreads();
    int cnt = sh[255]; if (cnt > BCAP) cnt = BCAP;

    for (int r = tid; r < NB; r += 256) {
        int c = bc[r];
        if (!c) continue;
        int off = bo[r];
        const uint32_t* sp = binned + (size_t)t * E + (size_t)r * CHUNK_E
                           + lStart[((size_t)t * NB + r) * KB + b];
        for (int i = 0; i < c; ++i) {
            int p = off + i;
            if (p < BCAP) {
                uint32_t v = sp[i];
                eL[p] = v;
                atomicAdd(&hist[v >> 17], 1);
            }
        }
    }
    __syncthreads();

    if (tid < BRANGE) excl[tid] = hist[tid];
    __syncthreads();
    for (int off = 1; off < BRANGE; off <<= 1) {
        int x = (tid < BRANGE && tid >= off) ? excl[tid - off] : 0;
        __syncthreads();
        if (tid < BRANGE) excl[tid] += x;
        __syncthreads();
    }
    if (tid < BRANGE) {
        int e_ = excl[tid] - hist[tid];
        cur[tid] = e_;
        int g = base + tid;
        if (g < N) {
            rp[(size_t)t * (N + 1) + g] = bstart + e_;
            dinv[(size_t)t * N + g] = rsqrtf(1.0f + (float)hist[tid]);
        }
    }
    __syncthreads();

    int* so = srcs + (size_t)t * E + bstart;
    for (int i = tid; i < cnt; i += 256) {
        uint32_t v = eL[i];
        int slot = atomicAdd(&cur[v >> 17], 1);
        so[slot] = (int)(v & 0x1FFFF);
    }
}

__global__ __launch_bounds__(256) void coef_kernel(
    float* __restrict__ coefs, const int* __restrict__ srcs,
    const float* __restrict__ dinv, int E, int N)
{
    int t = blockIdx.y;
    int e = blockIdx.x * 256 + threadIdx.x;
    if (e < E)
        coefs[(size_t)t * E + e] = dinv[(size_t)t * N + srcs[(size_t)t * E + e]];
}

// ===========================================================================
// MFMA fp16 GEMM (fp32 accumulate): H[N x BN] = act(X[N x 128]) @ W[128 x BN]
// ===========================================================================
template<int BN, bool RELU>
__global__ __launch_bounds__(256) void mfma_gemm_kernel(
    const float* __restrict__ X, const float* __restrict__ W,
    __half* __restrict__ H, int N)
{
    constexpr int BM = 64, K = 128;
    constexpr int XST = K + 8;
    constexpr int WST = K + 8;
    constexpr int LB = (BN == 128) ? 7 : 6;

    __shared__ _Float16 Xs[BM * XST];
    __shared__ _Float16 Ws[BN * WST];

    int tid = threadIdx.x;
    int row0 = blockIdx.x * BM;

#pragma unroll
    for (int u = 0; u < (BM * K / 4) / 256; ++u) {
        int i = u * 256 + tid;
        int r = i >> 5, c4 = i & 31;
        int gr = row0 + r;
        float4 v = make_float4(0.f, 0.f, 0.f, 0.f);
        if (gr < N) v = reinterpret_cast<const float4*>(X)[(size_t)gr * (K / 4) + c4];
        if (RELU) {
            v.x = fmaxf(v.x, 0.f); v.y = fmaxf(v.y, 0.f);
            v.z = fmaxf(v.z, 0.f); v.w = fmaxf(v.w, 0.f);
        }
        _Float16* xp = &Xs[r * XST + c4 * 4];
        xp[0] = (_Float16)v.x; xp[1] = (_Float16)v.y;
        xp[2] = (_Float16)v.z; xp[3] = (_Float16)v.w;
    }
    for (int idx = tid; idx < K * BN; idx += 256) {
        int k = idx >> LB, n = idx & (BN - 1);
        Ws[n * WST + k] = (_Float16)W[idx];
    }
    __syncthreads();

    int wv = tid >> 6, lane = tid & 63, quad = lane >> 4, lr = lane & 15;
    int rw = wv * 16;

    f16x8 a[4];
#pragma unroll
    for (int kk = 0; kk < 4; ++kk)
        a[kk] = *reinterpret_cast<const f16x8*>(&Xs[(rw + lr) * XST + quad * 8 + kk * 32]);

#pragma unroll
    for (int ct = 0; ct < BN / 16; ++ct) {
        f32x4v acc = {0.f, 0.f, 0.f, 0.f};
#pragma unroll
        for (int kk = 0; kk < 4; ++kk) {
            f16x8 bf = *reinterpret_cast<const f16x8*>(&Ws[(ct * 16 + lr) * WST + quad * 8 + kk * 32]);
            acc = __builtin_amdgcn_mfma_f32_16x16x32_f16(a[kk], bf, acc, 0, 0, 0);
        }
#pragma unroll
        for (int reg = 0; reg < 4; ++reg) {
            int gr = row0 + rw + quad * 4 + reg;
            if (gr < N) H[(size_t)gr * BN + ct * 16 + lr] = (__half)acc[reg];
        }
    }
}

// ===========================================================================
// CSR gather from fp16 H, fp32 accumulate, precomputed edge coefs.
// NPW nodes per wave; each group of 64/NPW lanes owns one node, 4 cols/lane.
// F=128: NPW=2 (32 lanes x 8B row reads). F=64: NPW=4 (16 lanes x 8B).
// ===========================================================================
template<int F, int NPW>
__global__ __launch_bounds__(256) void gather_csr_kernel(
    float* __restrict__ out, const __half* __restrict__ H,
    const float* __restrict__ dinv, const int* __restrict__ rp,
    const int* __restrict__ srcs, const float* __restrict__ coefs,
    const float* __restrict__ bias, int N, int accum)
{
    constexpr int LPG = 64 / NPW;            // lanes per node group
    constexpr int LSH = (LPG == 32) ? 5 : 4;
    static_assert(F == LPG * 4, "4 cols per lane");

    int wave = threadIdx.x >> 6;
    int lane = threadIdx.x & 63;
    int sub  = lane >> LSH;
    int lsub = lane & (LPG - 1);
    int i = (blockIdx.x * 4 + wave) * NPW + sub;
    if (i >= N) return;
    int c = lsub * 4;

    int beg = rp[i], end = rp[i + 1];
    float ax = 0.f, ay = 0.f, az = 0.f, aw = 0.f;

    auto h4fma = [&](float2 raw, float cf) {
        __half2 lo = *reinterpret_cast<__half2*>(&raw.x);
        __half2 hi = *reinterpret_cast<__half2*>(&raw.y);
        float2 l = __half22float2(lo), h = __half22float2(hi);
        ax = fmaf(l.x, cf, ax); ay = fmaf(l.y, cf, ay);
        az = fmaf(h.x, cf, az); aw = fmaf(h.y, cf, aw);
    };

    int j = beg;
    // prologue to 4-edge (16B) alignment
    int pre = (4 - (beg & 3)) & 3;
    pre = min(pre, end - beg);
    for (int k = 0; k < pre; ++k, ++j)
        h4fma(*reinterpret_cast<const float2*>(H + (size_t)srcs[j] * F + c), coefs[j]);
    // aligned int4/float4 main loop
    for (; j + 4 <= end; j += 4) {
        int4   s4 = *reinterpret_cast<const int4*>(srcs + j);
        float4 cf = *reinterpret_cast<const float4*>(coefs + j);
        float2 r0 = *reinterpret_cast<const float2*>(H + (size_t)s4.x * F + c);
        float2 r1 = *reinterpret_cast<const float2*>(H + (size_t)s4.y * F + c);
        float2 r2 = *reinterpret_cast<const float2*>(H + (size_t)s4.z * F + c);
        float2 r3 = *reinterpret_cast<const float2*>(H + (size_t)s4.w * F + c);
        h4fma(r0, cf.x); h4fma(r1, cf.y); h4fma(r2, cf.z); h4fma(r3, cf.w);
    }
    for (; j < end; ++j)
        h4fma(*reinterpret_cast<const float2*>(H + (size_t)srcs[j] * F + c), coefs[j]);

    float di = dinv[i];
    float2 hsr = *reinterpret_cast<const float2*>(H + (size_t)i * F + c);
    __half2 slo = *reinterpret_cast<__half2*>(&hsr.x);
    __half2 shi = *reinterpret_cast<__half2*>(&hsr.y);
    float2 sl = __half22float2(slo), sh2 = __half22float2(shi);
    float4 bv = *reinterpret_cast<const float4*>(bias + c);
    float dd = di * di;
    float4 r;
    r.x = (ax * di + sl.x  * dd + bv.x) * (1.0f / 3.0f);
    r.y = (ay * di + sl.y  * dd + bv.y) * (1.0f / 3.0f);
    r.z = (az * di + sh2.x * dd + bv.z) * (1.0f / 3.0f);
    r.w = (aw * di + sh2.y * dd + bv.w) * (1.0f / 3.0f);
    float* op = out + (size_t)i * F + c;
    if (accum) {
        float4 cu = *reinterpret_cast<const float4*>(op);
        r.x += cu.x; r.y += cu.y; r.z += cu.z; r.w += cu.w;
    }
    *reinterpret_cast<float4*>(op) = r;
}

// ===========================================================================
extern "C" void kernel_launch(void* const* d_in, const int* in_sizes, int n_in,
                              void* d_out, int out_size, void* d_ws, size_t ws_size,
                              hipStream_t stream) {
    const float* x     = (const float*)d_in[0];
    const int*   edges = (const int*)  d_in[1];
    const float* W1    = (const float*)d_in[2];
    const float* b1    = (const float*)d_in[3];
    const float* W2    = (const float*)d_in[4];
    const float* b2    = (const float*)d_in[5];
    float* out = (float*)d_out;

    const int N  = in_sizes[0] / F_IN;
    const int E  = in_sizes[1] / (T_REL * 2);
    const int KB = (N + BRANGE - 1) >> BSHIFT;       // 782 buckets/relation
    const int NB = (E + CHUNK_E - 1) / CHUNK_E;      // 391 bin blocks/relation

    auto align256 = [](size_t x_) { return (x_ + 255) & ~(size_t)255; };
    char* p = (char*)d_ws;
    float*  dinv   = (float*)p;  p += align256((size_t)T_REL * N * 4);
    int*    rp     = (int*)p;    p += align256((size_t)T_REL * (N + 1) * 4);
    int*    bstart = (int*)p;    p += align256((size_t)T_REL * (KB + 1) * 4);
    int*    colSum = (int*)p;    p += align256((size_t)T_REL * KB * 4);
    int*    bHist  = (int*)p;    p += align256((size_t)T_REL * NB * KB * 4);
    int*    lStart = (int*)p;    p += align256((size_t)T_REL * NB * KB * 4);
    int*    srcs   = (int*)p;    p += align256((size_t)T_REL * E * 4);
    float*  coefs  = (float*)p;  p += align256((size_t)T_REL * E * 4);
    __half* Hbuf   = (__half*)p; p += align256((size_t)N * F_HID * 2);
    float*  h1     = (float*)p;
    // binned (19.2 MB) overlays Hbuf (25.6 MB fp16): consumed before GEMM
    uint32_t* binned = (uint32_t*)Hbuf;

    // ---- CSR build ----
    hipMemsetAsync(colSum, 0, (size_t)T_REL * KB * sizeof(int), stream);
    {
        dim3 g(NB, T_REL);
        bin_dense_kernel<<<g, 256, 0, stream>>>(bHist, lStart, colSum, binned,
                                                edges, E, KB, NB);
    }
    bucket_scan_kernel<<<T_REL, 1024, 0, stream>>>(colSum, bstart, rp, KB, N, E);
    {
        dim3 g(KB, T_REL);
        bucket_gather_sort_kernel<<<g, 256, 0, stream>>>(
            bHist, lStart, bstart, binned, srcs, rp, dinv, KB, NB, N, E);
    }
    {
        dim3 g((E + 255) / 256, T_REL);
        coef_kernel<<<g, 256, 0, stream>>>(coefs, srcs, dinv, E, N);
    }

    // ---- layer 1: h1 = mean_t( GCNConv(x@W1[t]) + b1[t] ) ----
    for (int t = 0; t < T_REL; ++t) {
        mfma_gemm_kernel<128, false><<<(N + 63) / 64, 256, 0, stream>>>(
            x, W1 + (size_t)t * F_IN * F_HID, Hbuf, N);
        gather_csr_kernel<128, 2><<<(N + 7) / 8, 256, 0, stream>>>(
            h1, Hbuf, dinv + (size_t)t * N, rp + (size_t)t * (N + 1),
            srcs + (size_t)t * E, coefs + (size_t)t * E,
            b1 + (size_t)t * F_HID, N, t > 0 ? 1 : 0);
    }

    // ---- layer 2: out = mean_t( GCNConv(relu(h1)@W2[t]) + b2[t] ) ----
    for (int t = 0; t < T_REL; ++t) {
        mfma_gemm_kernel<64, true><<<(N + 63) / 64, 256, 0, stream>>>(
            h1, W2 + (size_t)t * F_HID * F_OUT, Hbuf, N);
        gather_csr_kernel<64, 4><<<(N + 15) / 16, 256, 0, stream>>>(
            out, Hbuf, dinv + (size_t)t * N, rp + (size_t)t * (N + 1),
            srcs + (size_t)t * E, coefs + (size_t)t * E,
            b2 + (size_t)t * F_OUT, N, t > 0 ? 1 : 0);
    }
}

// Round 8
// 658.332 us; speedup vs baseline: 3.2990x; 1.0914x over previous
//
#include <hip/hip_runtime.h>
#include <hip/hip_fp16.h>
#include <stdint.h>

#define T_REL 3
#define F_IN  128
#define F_HID 128
#define F_OUT 64

#define BSHIFT 7                 // 128 dst nodes per bucket
#define BRANGE (1 << BSHIFT)
#define BCAP   3072              // mean 2048, sigma ~45 -> 22 sigma headroom
#define KB_MAX 1024
#define CHUNK_E 4096             // edges per bin block
#define NB_MAX 512

typedef _Float16 f16x8 __attribute__((ext_vector_type(8)));
typedef float    f32x4v __attribute__((ext_vector_type(4)));

// ===========================================================================
// CSR build (unchanged from R7 except coef removed).
// ===========================================================================
__global__ __launch_bounds__(256) void bin_dense_kernel(
    int* __restrict__ bHist, int* __restrict__ lStart, int* __restrict__ colSum,
    uint32_t* __restrict__ binned, const int* __restrict__ edges,
    int E, int KB, int NB)
{
    int t = blockIdx.y, blk = blockIdx.x, tid = threadIdx.x;
    int e0 = blk * CHUNK_E;
    int cnt = min(CHUNK_E, E - e0);

    __shared__ int hist[KB_MAX];
    __shared__ int cursor[KB_MAX];
    __shared__ int sh[256];
    __shared__ uint32_t obuf[CHUNK_E];

    for (int b = tid; b < KB_MAX; b += 256) hist[b] = 0;
    __syncthreads();

    const int* srcA = edges + (size_t)(t * 2) * E;
    const int* dstA = edges + (size_t)(t * 2 + 1) * E;

    uint32_t pk[16]; int bk[16];
#pragma unroll
    for (int r = 0; r < 16; ++r) {
        int i = r * 256 + tid;
        if (i < cnt) {
            int s = srcA[e0 + i], d = dstA[e0 + i];
            bk[r] = d >> BSHIFT;
            pk[r] = ((uint32_t)(d & (BRANGE - 1)) << 17) | (uint32_t)s;
            atomicAdd(&hist[bk[r]], 1);
        } else bk[r] = -1;
    }
    __syncthreads();

    int b4 = tid * 4;
    int v0 = hist[b4], v1 = hist[b4 + 1], v2 = hist[b4 + 2], v3 = hist[b4 + 3];
    sh[tid] = v0 + v1 + v2 + v3;
    __syncthreads();
    for (int off = 1; off < 256; off <<= 1) {
        int x = (tid >= off) ? sh[tid - off] : 0;
        __syncthreads(); sh[tid] += x; __syncthreads();
    }
    int texcl = tid ? sh[tid - 1] : 0;
    cursor[b4] = texcl;
    cursor[b4 + 1] = texcl + v0;
    cursor[b4 + 2] = texcl + v0 + v1;
    cursor[b4 + 3] = texcl + v0 + v1 + v2;
    __syncthreads();

    int* bh = bHist + ((size_t)t * NB + blk) * KB;
    int* ls = lStart + ((size_t)t * NB + blk) * KB;
    for (int b = tid; b < KB; b += 256) {
        int h = hist[b];
        bh[b] = h; ls[b] = cursor[b];
        if (h) atomicAdd(&colSum[t * KB + b], h);
    }
    __syncthreads();

#pragma unroll
    for (int r = 0; r < 16; ++r) {
        if (bk[r] >= 0) {
            int pos = atomicAdd(&cursor[bk[r]], 1);
            obuf[pos] = pk[r];
        }
    }
    __syncthreads();

    for (int i = tid; i < cnt; i += 256)
        binned[(size_t)t * E + e0 + i] = obuf[i];
}

__global__ __launch_bounds__(1024) void bucket_scan_kernel(
    const int* __restrict__ colSum, int* __restrict__ bucketStart,
    int* __restrict__ rp, int KB, int N, int E)
{
    int t = blockIdx.x, tid = threadIdx.x;
    __shared__ int sh[1024];
    int v = (tid < KB) ? colSum[t * KB + tid] : 0;
    sh[tid] = v;
    __syncthreads();
    for (int off = 1; off < 1024; off <<= 1) {
        int x = (tid >= off) ? sh[tid - off] : 0;
        __syncthreads(); sh[tid] += x; __syncthreads();
    }
    if (tid < KB) bucketStart[t * (KB + 1) + tid] = sh[tid] - v;
    if (tid == 0) {
        bucketStart[t * (KB + 1) + KB] = E;
        rp[(size_t)t * (N + 1) + N] = E;
    }
}

__global__ __launch_bounds__(256) void bucket_gather_sort_kernel(
    const int* __restrict__ bHist, const int* __restrict__ lStart,
    const int* __restrict__ bucketStart, const uint32_t* __restrict__ binned,
    int* __restrict__ srcs, int* __restrict__ rp, float* __restrict__ dinv,
    int KB, int NB, int N, int E)
{
    int t = blockIdx.y, b = blockIdx.x, tid = threadIdx.x;
    int base = b << BSHIFT;
    int bstart = bucketStart[t * (KB + 1) + b];

    __shared__ uint32_t eL[BCAP];
    __shared__ int bc[NB_MAX], bo[NB_MAX];
    __shared__ int sh[256];
    __shared__ int hist[BRANGE], excl[BRANGE], cur[BRANGE];

    for (int r = tid; r < NB_MAX; r += 256) bc[r] = 0;
    if (tid < BRANGE) hist[tid] = 0;
    __syncthreads();
    for (int r = tid; r < NB; r += 256)
        bc[r] = bHist[((size_t)t * NB + r) * KB + b];
    __syncthreads();

    int i2 = tid * 2;
    int u0 = bc[i2], u1 = bc[i2 + 1];
    sh[tid] = u0 + u1;
    __syncthreads();
    for (int off = 1; off < 256; off <<= 1) {
        int x = (tid >= off) ? sh[tid - off] : 0;
        __syncthreads(); sh[tid] += x; __syncthreads();
    }
    int te = tid ? sh[tid - 1] : 0;
    bo[i2] = te; bo[i2 + 1] = te + u0;
    __syncthreads();
    int cnt = sh[255]; if (cnt > BCAP) cnt = BCAP;

    for (int r = tid; r < NB; r += 256) {
        int c = bc[r];
        if (!c) continue;
        int off = bo[r];
        const uint32_t* sp = binned + (size_t)t * E + (size_t)r * CHUNK_E
                           + lStart[((size_t)t * NB + r) * KB + b];
        for (int i = 0; i < c; ++i) {
            int p = off + i;
            if (p < BCAP) {
                uint32_t v = sp[i];
                eL[p] = v;
                atomicAdd(&hist[v >> 17], 1);
            }
        }
    }
    __syncthreads();

    if (tid < BRANGE) excl[tid] = hist[tid];
    __syncthreads();
    for (int off = 1; off < BRANGE; off <<= 1) {
        int x = (tid < BRANGE && tid >= off) ? excl[tid - off] : 0;
        __syncthreads();
        if (tid < BRANGE) excl[tid] += x;
        __syncthreads();
    }
    if (tid < BRANGE) {
        int e_ = excl[tid] - hist[tid];
        cur[tid] = e_;
        int g = base + tid;
        if (g < N) {
            rp[(size_t)t * (N + 1) + g] = bstart + e_;
            dinv[(size_t)t * N + g] = rsqrtf(1.0f + (float)hist[tid]);
        }
    }
    __syncthreads();

    int* so = srcs + (size_t)t * E + bstart;
    for (int i = tid; i < cnt; i += 256) {
        uint32_t v = eL[i];
        int slot = atomicAdd(&cur[v >> 17], 1);
        so[slot] = (int)(v & 0x1FFFF);
    }
}

// ===========================================================================
// MFMA fp16 GEMM, fused over relations via blockIdx.y = t:
// H[t][N x BN] = act(X[N x 128]) @ W[t][128 x BN]
// ===========================================================================
template<int BN, bool RELU>
__global__ __launch_bounds__(256) void mfma_gemm_kernel(
    const float* __restrict__ X, const float* __restrict__ W,
    __half* __restrict__ H, int N)
{
    constexpr int BM = 64, K = 128;
    constexpr int XST = K + 8;
    constexpr int WST = K + 8;
    constexpr int LB = (BN == 128) ? 7 : 6;

    __shared__ _Float16 Xs[BM * XST];
    __shared__ _Float16 Ws[BN * WST];

    int tid = threadIdx.x;
    int t   = blockIdx.y;
    int row0 = blockIdx.x * BM;
    const float* Wt = W + (size_t)t * K * BN;
    __half*      Ht = H + (size_t)t * N * BN;

#pragma unroll
    for (int u = 0; u < (BM * K / 4) / 256; ++u) {
        int i = u * 256 + tid;
        int r = i >> 5, c4 = i & 31;
        int gr = row0 + r;
        float4 v = make_float4(0.f, 0.f, 0.f, 0.f);
        if (gr < N) v = reinterpret_cast<const float4*>(X)[(size_t)gr * (K / 4) + c4];
        if (RELU) {
            v.x = fmaxf(v.x, 0.f); v.y = fmaxf(v.y, 0.f);
            v.z = fmaxf(v.z, 0.f); v.w = fmaxf(v.w, 0.f);
        }
        _Float16* xp = &Xs[r * XST + c4 * 4];
        xp[0] = (_Float16)v.x; xp[1] = (_Float16)v.y;
        xp[2] = (_Float16)v.z; xp[3] = (_Float16)v.w;
    }
    for (int idx = tid; idx < K * BN; idx += 256) {
        int k = idx >> LB, n = idx & (BN - 1);
        Ws[n * WST + k] = (_Float16)Wt[idx];
    }
    __syncthreads();

    int wv = tid >> 6, lane = tid & 63, quad = lane >> 4, lr = lane & 15;
    int rw = wv * 16;

    f16x8 a[4];
#pragma unroll
    for (int kk = 0; kk < 4; ++kk)
        a[kk] = *reinterpret_cast<const f16x8*>(&Xs[(rw + lr) * XST + quad * 8 + kk * 32]);

#pragma unroll
    for (int ct = 0; ct < BN / 16; ++ct) {
        f32x4v acc = {0.f, 0.f, 0.f, 0.f};
#pragma unroll
        for (int kk = 0; kk < 4; ++kk) {
            f16x8 bf = *reinterpret_cast<const f16x8*>(&Ws[(ct * 16 + lr) * WST + quad * 8 + kk * 32]);
            acc = __builtin_amdgcn_mfma_f32_16x16x32_f16(a[kk], bf, acc, 0, 0, 0);
        }
#pragma unroll
        for (int reg = 0; reg < 4; ++reg) {
            int gr = row0 + rw + quad * 4 + reg;
            if (gr < N) Ht[(size_t)gr * BN + ct * 16 + lr] = (__half)acc[reg];
        }
    }
}

// ===========================================================================
// Fused CSR gather: loops all T_REL relations per node, accumulates
// (edge sum + self-loop + bias) across t in registers, writes out ONCE.
// dinv[t][src] gathered inline (400 KB table, L2-resident, wave-broadcast).
// NPW nodes per wave; F=128: NPW=2 (32 lanes x 4 cols); F=64: NPW=4.
// ===========================================================================
template<int F, int NPW>
__global__ __launch_bounds__(256) void gather_fused_kernel(
    float* __restrict__ out, const __half* __restrict__ H,
    const float* __restrict__ dinv, const int* __restrict__ rp,
    const int* __restrict__ srcs, const float* __restrict__ bias,
    int N, int E)
{
    constexpr int LPG = 64 / NPW;
    constexpr int LSH = (LPG == 32) ? 5 : 4;
    static_assert(F == LPG * 4, "4 cols per lane");

    int wave = threadIdx.x >> 6;
    int lane = threadIdx.x & 63;
    int sub  = lane >> LSH;
    int lsub = lane & (LPG - 1);
    int i = (blockIdx.x * 4 + wave) * NPW + sub;
    if (i >= N) return;
    int c = lsub * 4;

    float rx = 0.f, ry = 0.f, rz = 0.f, rw_ = 0.f;

    for (int t = 0; t < T_REL; ++t) {
        const __half* Ht = H + (size_t)t * N * F;
        const float*  dv = dinv + (size_t)t * N;
        const int*    st = srcs + (size_t)t * E;
        const int*    rpt = rp + (size_t)t * (N + 1);

        float ax = 0.f, ay = 0.f, az = 0.f, aw = 0.f;
        auto h4fma = [&](float2 raw, float cf) {
            __half2 lo = *reinterpret_cast<__half2*>(&raw.x);
            __half2 hi = *reinterpret_cast<__half2*>(&raw.y);
            float2 l = __half22float2(lo), h = __half22float2(hi);
            ax = fmaf(l.x, cf, ax); ay = fmaf(l.y, cf, ay);
            az = fmaf(h.x, cf, az); aw = fmaf(h.y, cf, aw);
        };

        int beg = rpt[i], end = rpt[i + 1];
        int j = beg;
        int pre = (4 - (beg & 3)) & 3;
        pre = min(pre, end - beg);
        for (int k = 0; k < pre; ++k, ++j) {
            int s = st[j];
            h4fma(*reinterpret_cast<const float2*>(Ht + (size_t)s * F + c), dv[s]);
        }
        for (; j + 4 <= end; j += 4) {
            int4 s4 = *reinterpret_cast<const int4*>(st + j);
            float c0 = dv[s4.x], c1 = dv[s4.y], c2 = dv[s4.z], c3 = dv[s4.w];
            float2 r0 = *reinterpret_cast<const float2*>(Ht + (size_t)s4.x * F + c);
            float2 r1 = *reinterpret_cast<const float2*>(Ht + (size_t)s4.y * F + c);
            float2 r2 = *reinterpret_cast<const float2*>(Ht + (size_t)s4.z * F + c);
            float2 r3 = *reinterpret_cast<const float2*>(Ht + (size_t)s4.w * F + c);
            h4fma(r0, c0); h4fma(r1, c1); h4fma(r2, c2); h4fma(r3, c3);
        }
        for (; j < end; ++j) {
            int s = st[j];
            h4fma(*reinterpret_cast<const float2*>(Ht + (size_t)s * F + c), dv[s]);
        }

        float di = dv[i];
        float2 hsr = *reinterpret_cast<const float2*>(Ht + (size_t)i * F + c);
        __half2 slo = *reinterpret_cast<__half2*>(&hsr.x);
        __half2 shi = *reinterpret_cast<__half2*>(&hsr.y);
        float2 sl = __half22float2(slo), sh2 = __half22float2(shi);
        float4 bv = *reinterpret_cast<const float4*>(bias + (size_t)t * F + c);
        float dd = di * di;
        rx += ax * di + sl.x  * dd + bv.x;
        ry += ay * di + sl.y  * dd + bv.y;
        rz += az * di + sh2.x * dd + bv.z;
        rw_ += aw * di + sh2.y * dd + bv.w;
    }

    float4 r = make_float4(rx * (1.0f / 3.0f), ry * (1.0f / 3.0f),
                           rz * (1.0f / 3.0f), rw_ * (1.0f / 3.0f));
    *reinterpret_cast<float4*>(out + (size_t)i * F + c) = r;
}

// ===========================================================================
extern "C" void kernel_launch(void* const* d_in, const int* in_sizes, int n_in,
                              void* d_out, int out_size, void* d_ws, size_t ws_size,
                              hipStream_t stream) {
    const float* x     = (const float*)d_in[0];
    const int*   edges = (const int*)  d_in[1];
    const float* W1    = (const float*)d_in[2];
    const float* b1    = (const float*)d_in[3];
    const float* W2    = (const float*)d_in[4];
    const float* b2    = (const float*)d_in[5];
    float* out = (float*)d_out;

    const int N  = in_sizes[0] / F_IN;
    const int E  = in_sizes[1] / (T_REL * 2);
    const int KB = (N + BRANGE - 1) >> BSHIFT;       // 782 buckets/relation
    const int NB = (E + CHUNK_E - 1) / CHUNK_E;      // 391 bin blocks/relation

    auto align256 = [](size_t x_) { return (x_ + 255) & ~(size_t)255; };
    char* p = (char*)d_ws;
    float*  dinv   = (float*)p;  p += align256((size_t)T_REL * N * 4);
    int*    rp     = (int*)p;    p += align256((size_t)T_REL * (N + 1) * 4);
    int*    bstart = (int*)p;    p += align256((size_t)T_REL * (KB + 1) * 4);
    int*    colSum = (int*)p;    p += align256((size_t)T_REL * KB * 4);
    int*    bHist  = (int*)p;    p += align256((size_t)T_REL * NB * KB * 4);
    int*    lStart = (int*)p;    p += align256((size_t)T_REL * NB * KB * 4);
    int*    srcs   = (int*)p;    p += align256((size_t)T_REL * E * 4);
    __half* Hbuf   = (__half*)p; p += align256((size_t)T_REL * N * F_HID * 2);
    float*  h1     = (float*)p;  p += align256((size_t)N * F_HID * 4);
    // binned (19.2 MB) overlays h1 (51.2 MB fp32): binned fully consumed by
    // bucket_gather_sort, which precedes the layer-1 gather that writes h1.
    uint32_t* binned = (uint32_t*)h1;

    // ---- CSR build ----
    hipMemsetAsync(colSum, 0, (size_t)T_REL * KB * sizeof(int), stream);
    {
        dim3 g(NB, T_REL);
        bin_dense_kernel<<<g, 256, 0, stream>>>(bHist, lStart, colSum, binned,
                                                edges, E, KB, NB);
    }
    bucket_scan_kernel<<<T_REL, 1024, 0, stream>>>(colSum, bstart, rp, KB, N, E);
    {
        dim3 g(KB, T_REL);
        bucket_gather_sort_kernel<<<g, 256, 0, stream>>>(
            bHist, lStart, bstart, binned, srcs, rp, dinv, KB, NB, N, E);
    }

    // ---- layer 1: h1 = mean_t( GCNConv(x@W1[t]) + b1[t] ) ----
    {
        dim3 g((N + 63) / 64, T_REL);
        mfma_gemm_kernel<128, false><<<g, 256, 0, stream>>>(x, W1, Hbuf, N);
    }
    gather_fused_kernel<128, 2><<<(N + 7) / 8, 256, 0, stream>>>(
        h1, Hbuf, dinv, rp, srcs, b1, N, E);

    // ---- layer 2: out = mean_t( GCNConv(relu(h1)@W2[t]) + b2[t] ) ----
    {
        dim3 g((N + 63) / 64, T_REL);
        mfma_gemm_kernel<64, true><<<g, 256, 0, stream>>>(h1, W2, Hbuf, N);
    }
    gather_fused_kernel<64, 4><<<(N + 15) / 16, 256, 0, stream>>>(
        out, Hbuf, dinv, rp, srcs, b2, N, E);
}